// Round 16
// baseline (74.798 us; speedup 1.0000x reference)
//
#include <hip/hip_runtime.h>
#include <hip/hip_bf16.h>
#include <math.h>

#define B_ 2
#define N_ 2048
#define H_ 8
#define DH_ 64
#define DM_ 512
#define R_ 16
#define LAM_ 1.0f
#define SCALE_ 0.125f   // 1/sqrt(64)
#define LOG2E_ 1.44269504088896f
#define QSCALE_ (SCALE_ * LOG2E_)   // S emerges in log2 domain
#define DEFER_THR_ 11.5415603f      // 8 * log2e  (P bounded by e^8, as before)

typedef unsigned short u16;
typedef unsigned int u32;
typedef u16 u16x4 __attribute__((ext_vector_type(4)));
typedef u16 u16x8 __attribute__((ext_vector_type(8)));
typedef __bf16 bf16x8 __attribute__((ext_vector_type(8)));
typedef float f32x4 __attribute__((ext_vector_type(4)));

static __device__ __forceinline__ u16 f2bf(float f) {
    union { float f; unsigned u; } v; v.f = f;
    unsigned r = v.u + 0x7FFF + ((v.u >> 16) & 1);   // RNE
    return (u16)(r >> 16);
}

static __device__ __forceinline__ u32 pack_bf16(float lo, float hi) {
    float2 f2; f2.x = lo; f2.y = hi;
    __hip_bfloat162 h2 = __float22bfloat162_rn(f2);   // packed cvt
    u32 r;
    __builtin_memcpy(&r, &h2, 4);
    return r;
}

static __device__ __forceinline__ void gl_lds16(const void* g, void* l) {
    __builtin_amdgcn_global_load_lds(
        (const __attribute__((address_space(1))) unsigned*)g,
        (__attribute__((address_space(3))) unsigned*)l, 16, 0, 0);
}

// ---------------------------------------------------------------------------
// prep: bf16 casts only. y=0 -> x (2M), y=1..4 -> Wq,Wk,Wv,Wo (256K each)
// ---------------------------------------------------------------------------
__global__ __launch_bounds__(256) void prep(
    const float* __restrict__ x, const float* __restrict__ wq,
    const float* __restrict__ wk, const float* __restrict__ wv,
    const float* __restrict__ wo, u16* __restrict__ xb, u16* __restrict__ wqb,
    u16* __restrict__ wkb, u16* __restrict__ wvb, u16* __restrict__ wob) {
    int y = blockIdx.y;
    const float* src; u16* dst; int n;
    switch (y) {
        case 0: src = x;  dst = xb;  n = 2097152; break;
        case 1: src = wq; dst = wqb; n = 262144;  break;
        case 2: src = wk; dst = wkb; n = 262144;  break;
        case 3: src = wv; dst = wvb; n = 262144;  break;
        default: src = wo; dst = wob; n = 262144; break;
    }
    int i = (blockIdx.x * 256 + threadIdx.x) * 8;
    if (i >= n) return;
    float4 a = *(const float4*)(src + i);
    float4 b = *(const float4*)(src + i + 4);
    u16x8 o;
    o[0] = f2bf(a.x); o[1] = f2bf(a.y); o[2] = f2bf(a.z); o[3] = f2bf(a.w);
    o[4] = f2bf(b.x); o[5] = f2bf(b.y); o[6] = f2bf(b.z); o[7] = f2bf(b.w);
    *(u16x8*)(dst + i) = o;
}

// ---------------------------------------------------------------------------
// bf16 MFMA GEMM core v1: 64x64 tile, BK=64, 4 waves 32x32 each. (gemm_out)
// ---------------------------------------------------------------------------
struct Acc { f32x4 v[2][2]; };

static __device__ __forceinline__ Acc gemm_core(const u16* __restrict__ A,
                                                const u16* __restrict__ W,
                                                int m0, int nn0, char* LDSB) {
    int t = threadIdx.x, l = t & 63, w = t >> 6;
    int lg = l >> 4, li = l & 15;
    int wr = w >> 1, wc = w & 1;
    Acc acc;
#pragma unroll
    for (int m = 0; m < 2; ++m)
#pragma unroll
        for (int n = 0; n < 2; ++n) acc.v[m][n] = (f32x4){0.f, 0.f, 0.f, 0.f};

    int srl = l >> 3;
    int colb = ((l & 7) * 16) ^ (srl << 4);

    for (int k0 = 0; k0 < DM_; k0 += 64) {
        __syncthreads();
#pragma unroll
        for (int i = 0; i < 2; ++i) {
            int c = w * 2 + i;
            int row = c * 8 + srl;
            gl_lds16(A + (size_t)(m0 + row) * DM_ + k0 + (colb >> 1),
                     LDSB + c * 1024);
            gl_lds16(W + (size_t)(nn0 + row) * DM_ + k0 + (colb >> 1),
                     LDSB + 8192 + c * 1024);
        }
        __syncthreads();
#pragma unroll
        for (int kk = 0; kk < 2; ++kk) {
            bf16x8 af[2], bfr[2];
#pragma unroll
            for (int m = 0; m < 2; ++m) {
                int r = wr * 32 + m * 16 + li;
                af[m] = *(const bf16x8*)(LDSB + r * 128 +
                                         ((kk * 64 + lg * 16) ^ ((r & 7) << 4)));
            }
#pragma unroll
            for (int n = 0; n < 2; ++n) {
                int r = wc * 32 + n * 16 + li;
                bfr[n] = *(const bf16x8*)(LDSB + 8192 + r * 128 +
                                          ((kk * 64 + lg * 16) ^ ((r & 7) << 4)));
            }
#pragma unroll
            for (int m = 0; m < 2; ++m)
#pragma unroll
                for (int n = 0; n < 2; ++n)
                    acc.v[m][n] = __builtin_amdgcn_mfma_f32_16x16x32_bf16(
                        af[m], bfr[n], acc.v[m][n], 0, 0, 0);
        }
    }
    return acc;
}

// ---------------------------------------------------------------------------
// bf16 MFMA GEMM core v2: BM=128, BN=64, BK=64; wave = 64x32. (qkv)
// ---------------------------------------------------------------------------
struct Acc2 { f32x4 v[4][2]; };

static __device__ __forceinline__ Acc2 gemm_core2(const u16* __restrict__ A,
                                                  const u16* __restrict__ W,
                                                  int m0, int nn0, char* LDSB) {
    int t = threadIdx.x, l = t & 63, w = t >> 6;
    int lg = l >> 4, li = l & 15;
    int wr = w >> 1, wc = w & 1;
    Acc2 acc;
#pragma unroll
    for (int m = 0; m < 4; ++m)
#pragma unroll
        for (int n = 0; n < 2; ++n) acc.v[m][n] = (f32x4){0.f, 0.f, 0.f, 0.f};

    int srl = l >> 3;
    int colb = ((l & 7) * 16) ^ (srl << 4);

    for (int k0 = 0; k0 < DM_; k0 += 64) {
        __syncthreads();
#pragma unroll
        for (int i = 0; i < 4; ++i) {
            int c = w * 4 + i;
            int row = c * 8 + srl;
            gl_lds16(A + (size_t)(m0 + row) * DM_ + k0 + (colb >> 1),
                     LDSB + c * 1024);
        }
#pragma unroll
        for (int i = 0; i < 2; ++i) {
            int c = w * 2 + i;
            int row = c * 8 + srl;
            gl_lds16(W + (size_t)(nn0 + row) * DM_ + k0 + (colb >> 1),
                     LDSB + 16384 + c * 1024);
        }
        __syncthreads();
#pragma unroll
        for (int kk = 0; kk < 2; ++kk) {
            bf16x8 af[4], bfr[2];
#pragma unroll
            for (int m = 0; m < 4; ++m) {
                int r = wr * 64 + m * 16 + li;
                af[m] = *(const bf16x8*)(LDSB + r * 128 +
                                         ((kk * 64 + lg * 16) ^ ((r & 7) << 4)));
            }
#pragma unroll
            for (int n = 0; n < 2; ++n) {
                int r = wc * 32 + n * 16 + li;
                bfr[n] = *(const bf16x8*)(LDSB + 16384 + r * 128 +
                                          ((kk * 64 + lg * 16) ^ ((r & 7) << 4)));
            }
#pragma unroll
            for (int m = 0; m < 4; ++m)
#pragma unroll
                for (int n = 0; n < 2; ++n)
                    acc.v[m][n] = __builtin_amdgcn_mfma_f32_16x16x32_bf16(
                        af[m], bfr[n], acc.v[m][n], 0, 0, 0);
        }
    }
    return acc;
}

// ---------------------------------------------------------------------------
// qkv_fused: flat grid of 2832 blocks x 256 threads.
//   [0,768):     QKV GEMM (Q pre-scaled by SCALE*log2e -> log2-domain S)
//   [768,2816):  mask 64x64 tile scan
//   [2816,2832): rb = LAM*log2e*||pde rows||
// ---------------------------------------------------------------------------
__global__ __launch_bounds__(256) void qkv_fused(
    const u16* __restrict__ xb, const u16* __restrict__ wqb,
    const u16* __restrict__ wkb, const u16* __restrict__ wvb,
    const float* __restrict__ bq, const float* __restrict__ bk,
    const float* __restrict__ bv, const int* __restrict__ mask,
    const float* __restrict__ pde, u16* __restrict__ q_bf,
    u16* __restrict__ k_bf, u16* __restrict__ vt,
    float* __restrict__ rbs, int* __restrict__ flags) {
    __shared__ char LDSB[24576];
    int bid = blockIdx.x, t = threadIdx.x;

    if (bid < 768) {   // ---- QKV GEMM ----
        int y = bid >> 5;
        int which = y >> 3;
        int nn0 = (y & 7) * 64;
        const u16* W = which == 0 ? wqb : which == 1 ? wkb : wvb;
        const float* bias = which == 0 ? bq : which == 1 ? bk : bv;
        int m0 = (bid & 31) * 128;
        Acc2 acc = gemm_core2(xb, W, m0, nn0, LDSB);

        int l = t & 63, w = t >> 6;
        int lg = l >> 4, li = l & 15;
        int wr = w >> 1, wc = w & 1;
        float scale = which == 0 ? QSCALE_ : 1.0f;
#pragma unroll
        for (int n = 0; n < 2; ++n) {
            int col = nn0 + wc * 32 + n * 16 + li;
            float bv_ = bias[col];
            if (which < 2) {
                u16* dst = which == 0 ? q_bf : k_bf;
#pragma unroll
                for (int m = 0; m < 4; ++m)
#pragma unroll
                    for (int r = 0; r < 4; ++r) {
                        int row = m0 + wr * 64 + m * 16 + lg * 4 + r;
                        dst[(size_t)row * DM_ + col] =
                            f2bf((acc.v[m][n][r] + bv_) * scale);
                    }
            } else {
                int h = col >> 6, d = col & 63;
#pragma unroll
                for (int m = 0; m < 4; ++m) {
                    int row = m0 + wr * 64 + m * 16 + lg * 4;
                    int b = row >> 11, nb = row & (N_ - 1);
                    u16x4 o;
#pragma unroll
                    for (int r = 0; r < 4; ++r) o[r] = f2bf(acc.v[m][n][r] + bv_);
                    *(u16x4*)(vt + ((size_t)((b * 8 + h) * 64 + d)) * N_ + nb) = o;
                }
            }
        }
    } else if (bid < 2816) {   // ---- mask tile scan ----
        int idx = bid - 768;
        int b = idx >> 10, qt = (idx >> 5) & 31, kt = idx & 31;
        int* red = (int*)LDSB;
        if (t == 0) *red = 0;
        __syncthreads();
        int any = 0;
        for (int c = t; c < 1024; c += 256) {
            int row = c >> 4, seg = c & 15;
            int4 m4 = *(const int4*)(mask + (size_t)b * N_ * N_ +
                                     (size_t)(qt * 64 + row) * N_ + kt * 64 + seg * 4);
            any |= (m4.x == 0) | (m4.y == 0) | (m4.z == 0) | (m4.w == 0);
        }
        if (__ballot(any)) {
            if ((t & 63) == 0) atomicOr(red, 1);
        }
        __syncthreads();
        if (t == 0) flags[(b * 32 + qt) * 32 + kt] = *red;
    } else {   // ---- rb (log2-domain: * LOG2E) ----
        int i = (bid - 2816) * 256 + t;
        if (i >= B_ * N_) return;
        const float4* p = (const float4*)(pde + (size_t)i * R_);
        float s = 0.f;
#pragma unroll
        for (int j = 0; j < 4; ++j) {
            float4 v = p[j];
            s += v.x * v.x + v.y * v.y + v.z * v.z + v.w * v.w;
        }
        rbs[i] = LAM_ * LOG2E_ * sqrtf(s);
    }
}

// ---------------------------------------------------------------------------
// Output GEMM: 64x64 core, grid (64, 8) = 512 blocks = 2/CU.
// ---------------------------------------------------------------------------
__global__ __launch_bounds__(256) void gemm_out(
    const u16* __restrict__ aob, const u16* __restrict__ wob,
    const float* __restrict__ bo, float* __restrict__ out) {
    __shared__ char LDSB[24576];
    int nn0 = blockIdx.y * 64;
    int m0 = blockIdx.x * 64;
    Acc acc = gemm_core(aob, wob, m0, nn0, LDSB);

    int t = threadIdx.x, l = t & 63, w = t >> 6;
    int lg = l >> 4, li = l & 15;
    int wr = w >> 1, wc = w & 1;
#pragma unroll
    for (int n = 0; n < 2; ++n) {
        int col = nn0 + wc * 32 + n * 16 + li;
        float bv_ = bo[col];
#pragma unroll
        for (int m = 0; m < 2; ++m)
#pragma unroll
            for (int r = 0; r < 4; ++r) {
                int row = m0 + wr * 32 + m * 16 + lg * 4 + r;
                out[(size_t)row * DM_ + col] = acc.v[m][n][r] + bv_;
            }
    }
}

// ---------------------------------------------------------------------------
// attn11 = attn8 + log2-domain softmax (exp2, no per-elem mul) +
// shfl-free defer check (R10-proven) + per-lane deferred lrun (R10-proven).
// ---------------------------------------------------------------------------
__global__ __launch_bounds__(512) void attn11(
    const u16* __restrict__ qb, const u16* __restrict__ kb,
    const u16* __restrict__ vtb, const float* __restrict__ rbs,
    const int* __restrict__ mask, const int* __restrict__ flags,
    u16* __restrict__ aob) {
    __shared__ char KVB[2][2][16384];   // [group][buf][0..8191 K | 8192.. V^T]
    __shared__ char PsB[8][2048];       // per wave: [8 slots][16 li][16B]

    int t = threadIdx.x, l = t & 63, w = t >> 6;   // w 0..7
    int g2 = w >> 2, wq = w & 3;
    int raw = blockIdx.x;
    int sid = (raw & 7) * 64 + (raw >> 3);   // XCD-contiguous (512 % 8 == 0)
    int bh = sid >> 5, qg = sid & 31;
    int b = bh >> 3, h = bh & 7;
    int m0 = qg * 64 + wq * 16;              // this wave's 16 q-rows
    int lg = l >> 4, li = l & 15;
    int k0base = g2 * 1024;

    int srl = l >> 3;
    int colb = ((l & 7) * 16) ^ (srl << 4);  // pre-swizzled source col (bytes)

    // Q fragments (B-operand): lane holds Q[qrow=li][d=s*32+lg*8+j]
    bf16x8 qa[2];
    {
        const u16* qrow = qb + (size_t)(b * N_ + m0 + li) * DM_ + h * DH_;
        qa[0] = __builtin_bit_cast(bf16x8, *(const u16x8*)(qrow + lg * 8));
        qa[1] = __builtin_bit_cast(bf16x8, *(const u16x8*)(qrow + 32 + lg * 8));
    }

    f32x4 o[4];   // o[dt][r] = O^T[d=dt*16+lg*4+r][q=li]  (unnormalized)
#pragma unroll
    for (int dt = 0; dt < 4; ++dt) o[dt] = (f32x4){0.f, 0.f, 0.f, 0.f};
    float mrun = -INFINITY, lrun = 0.f;      // lrun per-lane, summed at end

    auto STAGE = [&](int bufi, int k0s) {
        char* base = &KVB[g2][bufi][0];
#pragma unroll
        for (int c = 0; c < 2; ++c) {
            int chunk = wq * 2 + c;
            int row = chunk * 8 + srl;
            gl_lds16(kb + (size_t)(b * N_ + k0s + row) * DM_ + h * DH_ + (colb >> 1),
                     base + chunk * 1024);
            gl_lds16(vtb + ((size_t)(bh * DH_ + row)) * N_ + k0s + (colb >> 1),
                     base + 8192 + chunk * 1024);
        }
    };

    STAGE(0, k0base);
    __syncthreads();

    // P write slot base per lane:
    //   slot(kt) = (kt>>1)*4 + (kt&1)*2 + (lg>>1); half = lg&1
    char* pwbase = &PsB[w][0] + li * 16 + ((lg & 1) << 3);
    int slot_lohi = (lg >> 1);

    int buf = 0;
    for (int tt = 0; tt < 16; ++tt) {
        int k0 = k0base + tt * 64;
        if (tt < 15) STAGE(buf ^ 1, k0 + 64);   // prefetch next tile

        const char* Kb = &KVB[g2][buf][0];
        const char* Vb = &KVB[g2][buf][8192];
        int flag = flags[(b * 32 + qg) * 32 + (k0 >> 6)];

        // ---- S^T = K.Q^T (log2-domain): st[kt][r], key=kt*16+lg*4+r, q=li --
        f32x4 st[4];
        __builtin_amdgcn_s_setprio(1);
#pragma unroll
        for (int kt = 0; kt < 4; ++kt) {
            st[kt] = (f32x4){0.f, 0.f, 0.f, 0.f};
#pragma unroll
            for (int s = 0; s < 2; ++s) {
                int key = kt * 16 + li;
                bf16x8 kf = *(const bf16x8*)(Kb + key * 128 +
                                             ((s * 64 + lg * 16) ^ ((key & 7) << 4)));
                st[kt] = __builtin_amdgcn_mfma_f32_16x16x32_bf16(kf, qa[s], st[kt],
                                                                 0, 0, 0);
            }
        }
        __builtin_amdgcn_s_setprio(0);

        // ---- bias (log2-domain rbs; keys consecutive in-lane) ----
#pragma unroll
        for (int kt = 0; kt < 4; ++kt) {
            float4 rb4 = *(const float4*)(rbs + b * N_ + k0 + kt * 16 + lg * 4);
            st[kt][0] -= rb4.x; st[kt][1] -= rb4.y;
            st[kt][2] -= rb4.z; st[kt][3] -= rb4.w;
        }
        if (flag) {
#pragma unroll
            for (int kt = 0; kt < 4; ++kt)
#pragma unroll
                for (int r = 0; r < 4; ++r) {
                    int rowg = m0 + li;
                    int keyg = k0 + kt * 16 + lg * 4 + r;
                    if (mask[(size_t)b * N_ * N_ + (size_t)rowg * N_ + keyg] == 0)
                        st[kt][r] = -INFINITY;
                }
        }

        // ---- shfl-free defer-max check (T13, R10-proven) ----
        float m0_ = fmaxf(fmaxf(st[0][0], st[0][1]), fmaxf(st[0][2], st[0][3]));
        float m1_ = fmaxf(fmaxf(st[1][0], st[1][1]), fmaxf(st[1][2], st[1][3]));
        float m2_ = fmaxf(fmaxf(st[2][0], st[2][1]), fmaxf(st[2][2], st[2][3]));
        float m3_ = fmaxf(fmaxf(st[3][0], st[3][1]), fmaxf(st[3][2], st[3][3]));
        float mymax = fmaxf(fmaxf(m0_, m1_), fmaxf(m2_, m3_));
        if (!__all(mymax - mrun <= DEFER_THR_)) {
            float pmax = mymax;
            pmax = fmaxf(pmax, __shfl_xor(pmax, 16));
            pmax = fmaxf(pmax, __shfl_xor(pmax, 32));
            float mnew = fmaxf(fmaxf(mrun, pmax), -3.0e38f);
            float corr = exp2f(mrun - mnew);
            mrun = mnew;
            lrun *= corr;
#pragma unroll
            for (int dt = 0; dt < 4; ++dt)
#pragma unroll
                for (int r = 0; r < 4; ++r) o[dt][r] *= corr;
        }

        // ---- P = 2^(S - m), packed cvt, slot write; per-lane lrun ----
#pragma unroll
        for (int kt = 0; kt < 4; ++kt) {
            float p0 = exp2f(st[kt][0] - mrun);
            float p1 = exp2f(st[kt][1] - mrun);
            float p2 = exp2f(st[kt][2] - mrun);
            float p3 = exp2f(st[kt][3] - mrun);
            lrun += (p0 + p1) + (p2 + p3);
            uint2 pkw;
            pkw.x = pack_bf16(p0, p1);
            pkw.y = pack_bf16(p2, p3);
            int slot = (kt >> 1) * 4 + (kt & 1) * 2 + slot_lohi;
            *(uint2*)(pwbase + (slot << 8)) = pkw;
        }

        // ---- O^T += V.P^T (pf read: 16 consecutive 16B per slot-row) ----
        bf16x8 pf[2];
#pragma unroll
        for (int s = 0; s < 2; ++s)
            pf[s] = *(const bf16x8*)(&PsB[w][0] + ((s * 4 + lg) << 8) + li * 16);
        __builtin_amdgcn_s_setprio(1);
#pragma unroll
        for (int dt = 0; dt < 4; ++dt)
#pragma unroll
            for (int s = 0; s < 2; ++s) {
                int d = dt * 16 + li;
                bf16x8 vf = *(const bf16x8*)(Vb + d * 128 +
                                             ((s * 64 + lg * 16) ^ ((d & 7) << 4)));
                o[dt] = __builtin_amdgcn_mfma_f32_16x16x32_bf16(vf, pf[s], o[dt],
                                                                0, 0, 0);
            }
        __builtin_amdgcn_s_setprio(0);

        __syncthreads();
        buf ^= 1;
    }

    // ---- quartet-sum the deferred lrun ----
    lrun += __shfl_xor(lrun, 16);
    lrun += __shfl_xor(lrun, 32);

    // ---- in-block combine of the two key-splits (O^T layout, padded) ----
    float* cmb = (float*)&KVB[0][0][0];   // 4 waves x [16 q][68] f32
    float* mlc = (float*)&PsB[0][0];      // 64 rows x 2 floats
    if (g2 == 1) {
        float* dst = cmb + wq * 1088;
#pragma unroll
        for (int dt = 0; dt < 4; ++dt)
            *(f32x4*)(dst + li * 68 + dt * 16 + lg * 4) = o[dt];
        if (lg == 0) {
            float2 ml; ml.x = mrun; ml.y = lrun;
            *(float2*)(mlc + (wq * 16 + li) * 2) = ml;
        }
    }
    __syncthreads();
    if (g2 == 0) {
        float2 ml1 = *(const float2*)(mlc + (wq * 16 + li) * 2);
        float m = fmaxf(mrun, ml1.x);
        float w0 = exp2f(mrun - m), w1 = exp2f(ml1.x - m);
        float denom = 1.f / (lrun * w0 + ml1.y * w1);
        w0 *= denom; w1 *= denom;
        const float* src = cmb + wq * 1088;
        u16* orow = aob + (size_t)(b * N_ + m0 + li) * DM_ + h * DH_;
#pragma unroll
        for (int dt = 0; dt < 4; ++dt) {
            f32x4 p1 = *(const f32x4*)(src + li * 68 + dt * 16 + lg * 4);
            u16x4 ov;
#pragma unroll
            for (int r = 0; r < 4; ++r)
                ov[r] = f2bf(o[dt][r] * w0 + p1[r] * w1);
            *(u16x4*)(orow + dt * 16 + lg * 4) = ov;
        }
    }
}

// ---------------------------------------------------------------------------
extern "C" void kernel_launch(void* const* d_in, const int* in_sizes, int n_in,
                              void* d_out, int out_size, void* d_ws, size_t ws_size,
                              hipStream_t stream) {
    const float* x   = (const float*)d_in[0];
    const float* pde = (const float*)d_in[1];
    const int*   msk = (const int*)d_in[2];
    const float* Wq  = (const float*)d_in[3];
    const float* bq  = (const float*)d_in[4];
    const float* Wk  = (const float*)d_in[5];
    const float* bk  = (const float*)d_in[6];
    const float* Wv  = (const float*)d_in[7];
    const float* bv  = (const float*)d_in[8];
    const float* Wo  = (const float*)d_in[9];
    const float* bo  = (const float*)d_in[10];
    float* out = (float*)d_out;

    const size_t MAT = (size_t)B_ * N_ * DM_;   // 2M elements
    const size_t WSZ = (size_t)DM_ * DM_;
    u16* xb   = (u16*)d_ws;
    u16* q_bf = xb + MAT;
    u16* k_bf = q_bf + MAT;
    u16* vt   = k_bf + MAT;
    u16* aob  = vt + MAT;
    u16* wqb  = aob + MAT;
    u16* wkb  = wqb + WSZ;
    u16* wvb  = wkb + WSZ;
    u16* wob  = wvb + WSZ;
    float* rbs = (float*)(wob + WSZ);
    int* flags = (int*)(rbs + B_ * N_);

    prep<<<dim3(1024, 5), 256, 0, stream>>>(x, Wq, Wk, Wv, Wo,
                                            xb, wqb, wkb, wvb, wob);

    qkv_fused<<<2832, 256, 0, stream>>>(xb, wqb, wkb, wvb, bq, bk, bv,
                                        msk, pde, q_bf, k_bf, vt, rbs, flags);

    attn11<<<512, 512, 0, stream>>>(q_bf, k_bf, vt, rbs, msk, flags, aob);

    gemm_out<<<dim3(64, 8), 256, 0, stream>>>(aob, wob, bo, out);
}

// Round 17
// 67.656 us; speedup vs baseline: 1.1056x; 1.1056x over previous
//
#include <hip/hip_runtime.h>
#include <hip/hip_bf16.h>
#include <math.h>

#define B_ 2
#define N_ 2048
#define H_ 8
#define DH_ 64
#define DM_ 512
#define R_ 16
#define LAM_ 1.0f
#define SCALE_ 0.125f   // 1/sqrt(64)
#define LOG2E_ 1.44269504088896f
#define QSCALE_ (SCALE_ * LOG2E_)   // S emerges in log2 domain
#define DEFER_THR_ 11.5415603f      // 8 * log2e  (P bounded by e^8, as before)

typedef unsigned short u16;
typedef unsigned int u32;
typedef u16 u16x4 __attribute__((ext_vector_type(4)));
typedef u16 u16x8 __attribute__((ext_vector_type(8)));
typedef __bf16 bf16x8 __attribute__((ext_vector_type(8)));
typedef float f32x4 __attribute__((ext_vector_type(4)));

#define EXP2(x) __builtin_amdgcn_exp2f(x)   // single v_exp_f32 (2^x)

static __device__ __forceinline__ u16 f2bf(float f) {
    union { float f; unsigned u; } v; v.f = f;
    unsigned r = v.u + 0x7FFF + ((v.u >> 16) & 1);   // RNE
    return (u16)(r >> 16);
}

static __device__ __forceinline__ u32 pack_bf16(float lo, float hi) {
    float2 f2; f2.x = lo; f2.y = hi;
    __hip_bfloat162 h2 = __float22bfloat162_rn(f2);   // packed cvt
    u32 r;
    __builtin_memcpy(&r, &h2, 4);
    return r;
}

static __device__ __forceinline__ void gl_lds16(const void* g, void* l) {
    __builtin_amdgcn_global_load_lds(
        (const __attribute__((address_space(1))) unsigned*)g,
        (__attribute__((address_space(3))) unsigned*)l, 16, 0, 0);
}

// ---------------------------------------------------------------------------
// prep: bf16 casts only. y=0 -> x (2M), y=1..4 -> Wq,Wk,Wv,Wo (256K each)
// ---------------------------------------------------------------------------
__global__ __launch_bounds__(256) void prep(
    const float* __restrict__ x, const float* __restrict__ wq,
    const float* __restrict__ wk, const float* __restrict__ wv,
    const float* __restrict__ wo, u16* __restrict__ xb, u16* __restrict__ wqb,
    u16* __restrict__ wkb, u16* __restrict__ wvb, u16* __restrict__ wob) {
    int y = blockIdx.y;
    const float* src; u16* dst; int n;
    switch (y) {
        case 0: src = x;  dst = xb;  n = 2097152; break;
        case 1: src = wq; dst = wqb; n = 262144;  break;
        case 2: src = wk; dst = wkb; n = 262144;  break;
        case 3: src = wv; dst = wvb; n = 262144;  break;
        default: src = wo; dst = wob; n = 262144; break;
    }
    int i = (blockIdx.x * 256 + threadIdx.x) * 8;
    if (i >= n) return;
    float4 a = *(const float4*)(src + i);
    float4 b = *(const float4*)(src + i + 4);
    u16x8 o;
    o[0] = f2bf(a.x); o[1] = f2bf(a.y); o[2] = f2bf(a.z); o[3] = f2bf(a.w);
    o[4] = f2bf(b.x); o[5] = f2bf(b.y); o[6] = f2bf(b.z); o[7] = f2bf(b.w);
    *(u16x8*)(dst + i) = o;
}

// ---------------------------------------------------------------------------
// bf16 MFMA GEMM core v1: 64x64 tile, BK=64, 4 waves 32x32 each. (gemm_out)
// ---------------------------------------------------------------------------
struct Acc { f32x4 v[2][2]; };

static __device__ __forceinline__ Acc gemm_core(const u16* __restrict__ A,
                                                const u16* __restrict__ W,
                                                int m0, int nn0, char* LDSB) {
    int t = threadIdx.x, l = t & 63, w = t >> 6;
    int lg = l >> 4, li = l & 15;
    int wr = w >> 1, wc = w & 1;
    Acc acc;
#pragma unroll
    for (int m = 0; m < 2; ++m)
#pragma unroll
        for (int n = 0; n < 2; ++n) acc.v[m][n] = (f32x4){0.f, 0.f, 0.f, 0.f};

    int srl = l >> 3;
    int colb = ((l & 7) * 16) ^ (srl << 4);

    for (int k0 = 0; k0 < DM_; k0 += 64) {
        __syncthreads();
#pragma unroll
        for (int i = 0; i < 2; ++i) {
            int c = w * 2 + i;
            int row = c * 8 + srl;
            gl_lds16(A + (size_t)(m0 + row) * DM_ + k0 + (colb >> 1),
                     LDSB + c * 1024);
            gl_lds16(W + (size_t)(nn0 + row) * DM_ + k0 + (colb >> 1),
                     LDSB + 8192 + c * 1024);
        }
        __syncthreads();
#pragma unroll
        for (int kk = 0; kk < 2; ++kk) {
            bf16x8 af[2], bfr[2];
#pragma unroll
            for (int m = 0; m < 2; ++m) {
                int r = wr * 32 + m * 16 + li;
                af[m] = *(const bf16x8*)(LDSB + r * 128 +
                                         ((kk * 64 + lg * 16) ^ ((r & 7) << 4)));
            }
#pragma unroll
            for (int n = 0; n < 2; ++n) {
                int r = wc * 32 + n * 16 + li;
                bfr[n] = *(const bf16x8*)(LDSB + 8192 + r * 128 +
                                          ((kk * 64 + lg * 16) ^ ((r & 7) << 4)));
            }
#pragma unroll
            for (int m = 0; m < 2; ++m)
#pragma unroll
                for (int n = 0; n < 2; ++n)
                    acc.v[m][n] = __builtin_amdgcn_mfma_f32_16x16x32_bf16(
                        af[m], bfr[n], acc.v[m][n], 0, 0, 0);
        }
    }
    return acc;
}

// ---------------------------------------------------------------------------
// bf16 MFMA GEMM core v2: BM=128, BN=64, BK=64; wave = 64x32. (qkv)
// ---------------------------------------------------------------------------
struct Acc2 { f32x4 v[4][2]; };

static __device__ __forceinline__ Acc2 gemm_core2(const u16* __restrict__ A,
                                                  const u16* __restrict__ W,
                                                  int m0, int nn0, char* LDSB) {
    int t = threadIdx.x, l = t & 63, w = t >> 6;
    int lg = l >> 4, li = l & 15;
    int wr = w >> 1, wc = w & 1;
    Acc2 acc;
#pragma unroll
    for (int m = 0; m < 4; ++m)
#pragma unroll
        for (int n = 0; n < 2; ++n) acc.v[m][n] = (f32x4){0.f, 0.f, 0.f, 0.f};

    int srl = l >> 3;
    int colb = ((l & 7) * 16) ^ (srl << 4);

    for (int k0 = 0; k0 < DM_; k0 += 64) {
        __syncthreads();
#pragma unroll
        for (int i = 0; i < 4; ++i) {
            int c = w * 4 + i;
            int row = c * 8 + srl;
            gl_lds16(A + (size_t)(m0 + row) * DM_ + k0 + (colb >> 1),
                     LDSB + c * 1024);
        }
#pragma unroll
        for (int i = 0; i < 2; ++i) {
            int c = w * 2 + i;
            int row = c * 8 + srl;
            gl_lds16(W + (size_t)(nn0 + row) * DM_ + k0 + (colb >> 1),
                     LDSB + 16384 + c * 1024);
        }
        __syncthreads();
#pragma unroll
        for (int kk = 0; kk < 2; ++kk) {
            bf16x8 af[4], bfr[2];
#pragma unroll
            for (int m = 0; m < 4; ++m) {
                int r = wr * 64 + m * 16 + li;
                af[m] = *(const bf16x8*)(LDSB + r * 128 +
                                         ((kk * 64 + lg * 16) ^ ((r & 7) << 4)));
            }
#pragma unroll
            for (int n = 0; n < 2; ++n) {
                int r = wc * 32 + n * 16 + li;
                bfr[n] = *(const bf16x8*)(LDSB + 16384 + r * 128 +
                                          ((kk * 64 + lg * 16) ^ ((r & 7) << 4)));
            }
#pragma unroll
            for (int m = 0; m < 4; ++m)
#pragma unroll
                for (int n = 0; n < 2; ++n)
                    acc.v[m][n] = __builtin_amdgcn_mfma_f32_16x16x32_bf16(
                        af[m], bfr[n], acc.v[m][n], 0, 0, 0);
        }
    }
    return acc;
}

// ---------------------------------------------------------------------------
// qkv_fused: flat grid of 2832 blocks x 256 threads.
//   [0,768):     QKV GEMM (Q pre-scaled by SCALE*log2e -> log2-domain S)
//   [768,2816):  mask 64x64 tile scan
//   [2816,2832): rb = LAM*log2e*||pde rows||
// ---------------------------------------------------------------------------
__global__ __launch_bounds__(256) void qkv_fused(
    const u16* __restrict__ xb, const u16* __restrict__ wqb,
    const u16* __restrict__ wkb, const u16* __restrict__ wvb,
    const float* __restrict__ bq, const float* __restrict__ bk,
    const float* __restrict__ bv, const int* __restrict__ mask,
    const float* __restrict__ pde, u16* __restrict__ q_bf,
    u16* __restrict__ k_bf, u16* __restrict__ vt,
    float* __restrict__ rbs, int* __restrict__ flags) {
    __shared__ char LDSB[24576];
    int bid = blockIdx.x, t = threadIdx.x;

    if (bid < 768) {   // ---- QKV GEMM ----
        int y = bid >> 5;
        int which = y >> 3;
        int nn0 = (y & 7) * 64;
        const u16* W = which == 0 ? wqb : which == 1 ? wkb : wvb;
        const float* bias = which == 0 ? bq : which == 1 ? bk : bv;
        int m0 = (bid & 31) * 128;
        Acc2 acc = gemm_core2(xb, W, m0, nn0, LDSB);

        int l = t & 63, w = t >> 6;
        int lg = l >> 4, li = l & 15;
        int wr = w >> 1, wc = w & 1;
        float scale = which == 0 ? QSCALE_ : 1.0f;
#pragma unroll
        for (int n = 0; n < 2; ++n) {
            int col = nn0 + wc * 32 + n * 16 + li;
            float bv_ = bias[col];
            if (which < 2) {
                u16* dst = which == 0 ? q_bf : k_bf;
#pragma unroll
                for (int m = 0; m < 4; ++m)
#pragma unroll
                    for (int r = 0; r < 4; ++r) {
                        int row = m0 + wr * 64 + m * 16 + lg * 4 + r;
                        dst[(size_t)row * DM_ + col] =
                            f2bf((acc.v[m][n][r] + bv_) * scale);
                    }
            } else {
                int h = col >> 6, d = col & 63;
#pragma unroll
                for (int m = 0; m < 4; ++m) {
                    int row = m0 + wr * 64 + m * 16 + lg * 4;
                    int b = row >> 11, nb = row & (N_ - 1);
                    u16x4 o;
#pragma unroll
                    for (int r = 0; r < 4; ++r) o[r] = f2bf(acc.v[m][n][r] + bv_);
                    *(u16x4*)(vt + ((size_t)((b * 8 + h) * 64 + d)) * N_ + nb) = o;
                }
            }
        }
    } else if (bid < 2816) {   // ---- mask tile scan ----
        int idx = bid - 768;
        int b = idx >> 10, qt = (idx >> 5) & 31, kt = idx & 31;
        int* red = (int*)LDSB;
        if (t == 0) *red = 0;
        __syncthreads();
        int any = 0;
        for (int c = t; c < 1024; c += 256) {
            int row = c >> 4, seg = c & 15;
            int4 m4 = *(const int4*)(mask + (size_t)b * N_ * N_ +
                                     (size_t)(qt * 64 + row) * N_ + kt * 64 + seg * 4);
            any |= (m4.x == 0) | (m4.y == 0) | (m4.z == 0) | (m4.w == 0);
        }
        if (__ballot(any)) {
            if ((t & 63) == 0) atomicOr(red, 1);
        }
        __syncthreads();
        if (t == 0) flags[(b * 32 + qt) * 32 + kt] = *red;
    } else {   // ---- rb (log2-domain: * LOG2E) ----
        int i = (bid - 2816) * 256 + t;
        if (i >= B_ * N_) return;
        const float4* p = (const float4*)(pde + (size_t)i * R_);
        float s = 0.f;
#pragma unroll
        for (int j = 0; j < 4; ++j) {
            float4 v = p[j];
            s += v.x * v.x + v.y * v.y + v.z * v.z + v.w * v.w;
        }
        rbs[i] = LAM_ * LOG2E_ * sqrtf(s);
    }
}

// ---------------------------------------------------------------------------
// Output GEMM: 64x64 core, grid (64, 8) = 512 blocks = 2/CU.
// ---------------------------------------------------------------------------
__global__ __launch_bounds__(256) void gemm_out(
    const u16* __restrict__ aob, const u16* __restrict__ wob,
    const float* __restrict__ bo, float* __restrict__ out) {
    __shared__ char LDSB[24576];
    int nn0 = blockIdx.y * 64;
    int m0 = blockIdx.x * 64;
    Acc acc = gemm_core(aob, wob, m0, nn0, LDSB);

    int t = threadIdx.x, l = t & 63, w = t >> 6;
    int lg = l >> 4, li = l & 15;
    int wr = w >> 1, wc = w & 1;
#pragma unroll
    for (int n = 0; n < 2; ++n) {
        int col = nn0 + wc * 32 + n * 16 + li;
        float bv_ = bo[col];
#pragma unroll
        for (int m = 0; m < 2; ++m)
#pragma unroll
            for (int r = 0; r < 4; ++r) {
                int row = m0 + wr * 32 + m * 16 + lg * 4 + r;
                out[(size_t)row * DM_ + col] = acc.v[m][n][r] + bv_;
            }
    }
}

// ---------------------------------------------------------------------------
// attn12 = attn11 with raw v_exp_f32 (EXP2 builtin) — 1 VALU op per P elem.
// log2-domain softmax, shfl-free defer check, per-lane deferred lrun,
// conflict-free P slots, padded combine.
// ---------------------------------------------------------------------------
__global__ __launch_bounds__(512) void attn12(
    const u16* __restrict__ qb, const u16* __restrict__ kb,
    const u16* __restrict__ vtb, const float* __restrict__ rbs,
    const int* __restrict__ mask, const int* __restrict__ flags,
    u16* __restrict__ aob) {
    __shared__ char KVB[2][2][16384];   // [group][buf][0..8191 K | 8192.. V^T]
    __shared__ char PsB[8][2048];       // per wave: [8 slots][16 li][16B]

    int t = threadIdx.x, l = t & 63, w = t >> 6;   // w 0..7
    int g2 = w >> 2, wq = w & 3;
    int raw = blockIdx.x;
    int sid = (raw & 7) * 64 + (raw >> 3);   // XCD-contiguous (512 % 8 == 0)
    int bh = sid >> 5, qg = sid & 31;
    int b = bh >> 3, h = bh & 7;
    int m0 = qg * 64 + wq * 16;              // this wave's 16 q-rows
    int lg = l >> 4, li = l & 15;
    int k0base = g2 * 1024;

    int srl = l >> 3;
    int colb = ((l & 7) * 16) ^ (srl << 4);  // pre-swizzled source col (bytes)

    // Q fragments (B-operand): lane holds Q[qrow=li][d=s*32+lg*8+j]
    bf16x8 qa[2];
    {
        const u16* qrow = qb + (size_t)(b * N_ + m0 + li) * DM_ + h * DH_;
        qa[0] = __builtin_bit_cast(bf16x8, *(const u16x8*)(qrow + lg * 8));
        qa[1] = __builtin_bit_cast(bf16x8, *(const u16x8*)(qrow + 32 + lg * 8));
    }

    f32x4 o[4];   // o[dt][r] = O^T[d=dt*16+lg*4+r][q=li]  (unnormalized)
#pragma unroll
    for (int dt = 0; dt < 4; ++dt) o[dt] = (f32x4){0.f, 0.f, 0.f, 0.f};
    float mrun = -INFINITY, lrun = 0.f;      // lrun per-lane, summed at end

    auto STAGE = [&](int bufi, int k0s) {
        char* base = &KVB[g2][bufi][0];
#pragma unroll
        for (int c = 0; c < 2; ++c) {
            int chunk = wq * 2 + c;
            int row = chunk * 8 + srl;
            gl_lds16(kb + (size_t)(b * N_ + k0s + row) * DM_ + h * DH_ + (colb >> 1),
                     base + chunk * 1024);
            gl_lds16(vtb + ((size_t)(bh * DH_ + row)) * N_ + k0s + (colb >> 1),
                     base + 8192 + chunk * 1024);
        }
    };

    STAGE(0, k0base);
    __syncthreads();

    // P write slot base per lane:
    //   slot(kt) = (kt>>1)*4 + (kt&1)*2 + (lg>>1); half = lg&1
    char* pwbase = &PsB[w][0] + li * 16 + ((lg & 1) << 3);
    int slot_lohi = (lg >> 1);

    int buf = 0;
    for (int tt = 0; tt < 16; ++tt) {
        int k0 = k0base + tt * 64;
        if (tt < 15) STAGE(buf ^ 1, k0 + 64);   // prefetch next tile

        const char* Kb = &KVB[g2][buf][0];
        const char* Vb = &KVB[g2][buf][8192];
        int flag = flags[(b * 32 + qg) * 32 + (k0 >> 6)];

        // ---- S^T = K.Q^T (log2-domain): st[kt][r], key=kt*16+lg*4+r, q=li --
        f32x4 st[4];
        __builtin_amdgcn_s_setprio(1);
#pragma unroll
        for (int kt = 0; kt < 4; ++kt) {
            st[kt] = (f32x4){0.f, 0.f, 0.f, 0.f};
#pragma unroll
            for (int s = 0; s < 2; ++s) {
                int key = kt * 16 + li;
                bf16x8 kf = *(const bf16x8*)(Kb + key * 128 +
                                             ((s * 64 + lg * 16) ^ ((key & 7) << 4)));
                st[kt] = __builtin_amdgcn_mfma_f32_16x16x32_bf16(kf, qa[s], st[kt],
                                                                 0, 0, 0);
            }
        }
        __builtin_amdgcn_s_setprio(0);

        // ---- bias (log2-domain rbs; keys consecutive in-lane) ----
#pragma unroll
        for (int kt = 0; kt < 4; ++kt) {
            float4 rb4 = *(const float4*)(rbs + b * N_ + k0 + kt * 16 + lg * 4);
            st[kt][0] -= rb4.x; st[kt][1] -= rb4.y;
            st[kt][2] -= rb4.z; st[kt][3] -= rb4.w;
        }
        if (flag) {
#pragma unroll
            for (int kt = 0; kt < 4; ++kt)
#pragma unroll
                for (int r = 0; r < 4; ++r) {
                    int rowg = m0 + li;
                    int keyg = k0 + kt * 16 + lg * 4 + r;
                    if (mask[(size_t)b * N_ * N_ + (size_t)rowg * N_ + keyg] == 0)
                        st[kt][r] = -INFINITY;
                }
        }

        // ---- shfl-free defer-max check (T13) ----
        float m0_ = fmaxf(fmaxf(st[0][0], st[0][1]), fmaxf(st[0][2], st[0][3]));
        float m1_ = fmaxf(fmaxf(st[1][0], st[1][1]), fmaxf(st[1][2], st[1][3]));
        float m2_ = fmaxf(fmaxf(st[2][0], st[2][1]), fmaxf(st[2][2], st[2][3]));
        float m3_ = fmaxf(fmaxf(st[3][0], st[3][1]), fmaxf(st[3][2], st[3][3]));
        float mymax = fmaxf(fmaxf(m0_, m1_), fmaxf(m2_, m3_));
        if (!__all(mymax - mrun <= DEFER_THR_)) {
            float pmax = mymax;
            pmax = fmaxf(pmax, __shfl_xor(pmax, 16));
            pmax = fmaxf(pmax, __shfl_xor(pmax, 32));
            float mnew = fmaxf(fmaxf(mrun, pmax), -3.0e38f);
            float corr = EXP2(mrun - mnew);
            mrun = mnew;
            lrun *= corr;
#pragma unroll
            for (int dt = 0; dt < 4; ++dt)
#pragma unroll
                for (int r = 0; r < 4; ++r) o[dt][r] *= corr;
        }

        // ---- P = 2^(S - m) [1 op each], packed cvt, slot write ----
#pragma unroll
        for (int kt = 0; kt < 4; ++kt) {
            float p0 = EXP2(st[kt][0] - mrun);
            float p1 = EXP2(st[kt][1] - mrun);
            float p2 = EXP2(st[kt][2] - mrun);
            float p3 = EXP2(st[kt][3] - mrun);
            lrun += (p0 + p1) + (p2 + p3);
            uint2 pkw;
            pkw.x = pack_bf16(p0, p1);
            pkw.y = pack_bf16(p2, p3);
            int slot = (kt >> 1) * 4 + (kt & 1) * 2 + slot_lohi;
            *(uint2*)(pwbase + (slot << 8)) = pkw;
        }

        // ---- O^T += V.P^T (pf read: 16 consecutive 16B per slot-row) ----
        bf16x8 pf[2];
#pragma unroll
        for (int s = 0; s < 2; ++s)
            pf[s] = *(const bf16x8*)(&PsB[w][0] + ((s * 4 + lg) << 8) + li * 16);
        __builtin_amdgcn_s_setprio(1);
#pragma unroll
        for (int dt = 0; dt < 4; ++dt)
#pragma unroll
            for (int s = 0; s < 2; ++s) {
                int d = dt * 16 + li;
                bf16x8 vf = *(const bf16x8*)(Vb + d * 128 +
                                             ((s * 64 + lg * 16) ^ ((d & 7) << 4)));
                o[dt] = __builtin_amdgcn_mfma_f32_16x16x32_bf16(vf, pf[s], o[dt],
                                                                0, 0, 0);
            }
        __builtin_amdgcn_s_setprio(0);

        __syncthreads();
        buf ^= 1;
    }

    // ---- quartet-sum the deferred lrun ----
    lrun += __shfl_xor(lrun, 16);
    lrun += __shfl_xor(lrun, 32);

    // ---- in-block combine of the two key-splits (O^T layout, padded) ----
    float* cmb = (float*)&KVB[0][0][0];   // 4 waves x [16 q][68] f32
    float* mlc = (float*)&PsB[0][0];      // 64 rows x 2 floats
    if (g2 == 1) {
        float* dst = cmb + wq * 1088;
#pragma unroll
        for (int dt = 0; dt < 4; ++dt)
            *(f32x4*)(dst + li * 68 + dt * 16 + lg * 4) = o[dt];
        if (lg == 0) {
            float2 ml; ml.x = mrun; ml.y = lrun;
            *(float2*)(mlc + (wq * 16 + li) * 2) = ml;
        }
    }
    __syncthreads();
    if (g2 == 0) {
        float2 ml1 = *(const float2*)(mlc + (wq * 16 + li) * 2);
        float m = fmaxf(mrun, ml1.x);
        float w0 = EXP2(mrun - m), w1 = EXP2(ml1.x - m);
        float denom = 1.f / (lrun * w0 + ml1.y * w1);
        w0 *= denom; w1 *= denom;
        const float* src = cmb + wq * 1088;
        u16* orow = aob + (size_t)(b * N_ + m0 + li) * DM_ + h * DH_;
#pragma unroll
        for (int dt = 0; dt < 4; ++dt) {
            f32x4 p1 = *(const f32x4*)(src + li * 68 + dt * 16 + lg * 4);
            u16x4 ov;
#pragma unroll
            for (int r = 0; r < 4; ++r)
                ov[r] = f2bf(o[dt][r] * w0 + p1[r] * w1);
            *(u16x4*)(orow + dt * 16 + lg * 4) = ov;
        }
    }
}

// ---------------------------------------------------------------------------
extern "C" void kernel_launch(void* const* d_in, const int* in_sizes, int n_in,
                              void* d_out, int out_size, void* d_ws, size_t ws_size,
                              hipStream_t stream) {
    const float* x   = (const float*)d_in[0];
    const float* pde = (const float*)d_in[1];
    const int*   msk = (const int*)d_in[2];
    const float* Wq  = (const float*)d_in[3];
    const float* bq  = (const float*)d_in[4];
    const float* Wk  = (const float*)d_in[5];
    const float* bk  = (const float*)d_in[6];
    const float* Wv  = (const float*)d_in[7];
    const float* bv  = (const float*)d_in[8];
    const float* Wo  = (const float*)d_in[9];
    const float* bo  = (const float*)d_in[10];
    float* out = (float*)d_out;

    const size_t MAT = (size_t)B_ * N_ * DM_;   // 2M elements
    const size_t WSZ = (size_t)DM_ * DM_;
    u16* xb   = (u16*)d_ws;
    u16* q_bf = xb + MAT;
    u16* k_bf = q_bf + MAT;
    u16* vt   = k_bf + MAT;
    u16* aob  = vt + MAT;
    u16* wqb  = aob + MAT;
    u16* wkb  = wqb + WSZ;
    u16* wvb  = wkb + WSZ;
    u16* wob  = wvb + WSZ;
    float* rbs = (float*)(wob + WSZ);
    int* flags = (int*)(rbs + B_ * N_);

    prep<<<dim3(1024, 5), 256, 0, stream>>>(x, Wq, Wk, Wv, Wo,
                                            xb, wqb, wkb, wvb, wob);

    qkv_fused<<<2832, 256, 0, stream>>>(xb, wqb, wkb, wvb, bq, bk, bv,
                                        msk, pde, q_bf, k_bf, vt, rbs, flags);

    attn12<<<512, 512, 0, stream>>>(q_bf, k_bf, vt, rbs, msk, flags, aob);

    gemm_out<<<dim3(64, 8), 256, 0, stream>>>(aob, wob, bo, out);
}